// Round 6
// baseline (1820.143 us; speedup 1.0000x reference)
//
#include <hip/hip_runtime.h>
#include <hip/hip_bf16.h>
#include <hip/hip_fp16.h>

// Problem: B=64, S=512, E=768, H=256 (4H=1024). Bidirectional relu-LSTM + dense(2).
#define B_ 64
#define S_ 512
#define E_ 768
#define H_ 256
#define G_ 1024  // 4H
#define MROWS 32768  // B*S per direction

typedef float f32x4 __attribute__((ext_vector_type(4)));
typedef float f32x16 __attribute__((ext_vector_type(16)));
typedef short short8 __attribute__((ext_vector_type(8)));
typedef _Float16 v2h __attribute__((ext_vector_type(2)));
typedef _Float16 h8 __attribute__((ext_vector_type(8)));
typedef unsigned int u32x4 __attribute__((ext_vector_type(4)));

// ---------------- prep kernels ----------------

__global__ void cast_x_kernel(const float* __restrict__ x, __hip_bfloat16* __restrict__ xbf, int n) {
    int i = (blockIdx.x * 256 + threadIdx.x) * 4;
    if (i >= n) return;
    float4 v = *(const float4*)(x + i);
    xbf[i + 0] = __float2bfloat16(v.x);
    xbf[i + 1] = __float2bfloat16(v.y);
    xbf[i + 2] = __float2bfloat16(v.z);
    xbf[i + 3] = __float2bfloat16(v.w);
}

// kernel [E][G] fp32 -> kT [dir][G][E] bf16 (transposed for MFMA B-fragments)
__global__ void prep_kT_kernel(const float* __restrict__ kf, const float* __restrict__ kb,
                               __hip_bfloat16* __restrict__ kT) {
    int idx = blockIdx.x * 256 + threadIdx.x;   // over E_*G_
    int dir = blockIdx.y;
    const float* src = dir ? kb : kf;
    int k = idx >> 10;        // E index
    int n = idx & 1023;       // G index
    float v = src[idx];       // coalesced read (n fast)
    kT[(size_t)dir * G_ * E_ + (size_t)n * E_ + k] = __float2bfloat16(v);
}

// rec [256][1024] fp32 -> recF: A-fragments of rec^T for mfma_f32_16x16x32_f16.
// A-matrix (per gc-tile of 16): A[m=gc-in-tile][k], lane l holds m=l&15,
// k = kstep*32 + (l>>4)*8 + j (j=0..7), packed as uint4 (8 f16).
// recF[dir][tile(64)][kstep(8)][lane(64)] uint4  -> 2*64*8*64*16B = 1 MB.
__global__ void prep_recF_kernel(const float* __restrict__ rf_, const float* __restrict__ rb_,
                                 uint4* __restrict__ recF) {
    int idx = blockIdx.x * 256 + threadIdx.x;   // 0..65535
    int dir = idx >> 15;
    const float* src = dir ? rb_ : rf_;
    int li   = idx & 63;
    int ks   = (idx >> 6) & 7;
    int tile = (idx >> 9) & 63;
    int gc = tile * 16 + (li & 15);
    int k0 = ks * 32 + (li >> 4) * 8;
    unsigned int wds[4];
#pragma unroll
    for (int u = 0; u < 4; ++u) {
        _Float16 a  = (_Float16)src[(size_t)(k0 + 2 * u) * G_ + gc];
        _Float16 b2 = (_Float16)src[(size_t)(k0 + 2 * u + 1) * G_ + gc];
        wds[u] = (unsigned int)__builtin_bit_cast(unsigned short, a) |
                 ((unsigned int)__builtin_bit_cast(unsigned short, b2) << 16);
    }
    uint4 q; q.x = wds[0]; q.y = wds[1]; q.z = wds[2]; q.w = wds[3];
    recF[idx] = q;
}

// ---------------- xz GEMM: LDS-tiled 128x128, BK=32, mfma 32x32x16 (unchanged) --------
#define TM 128
#define TN 128
#define BK 32
#define LDA 40   // padded LDS row stride in elements

__global__ __launch_bounds__(256) void gemm_xz_kernel(
        const __hip_bfloat16* __restrict__ xbf,   // [B*S][E]
        const __hip_bfloat16* __restrict__ kT,    // [2][G][E]
        const float* __restrict__ bias_f, const float* __restrict__ bias_b,
        __hip_bfloat16* __restrict__ xz) {        // [2][MROWS][G]
    int dir  = blockIdx.z;
    int nblk = blockIdx.x;      // 0..7   (G/128)
    int mblk = blockIdx.y;      // 0..255 (MROWS/128)
    int tid  = threadIdx.x;
    int wave = tid >> 6, lane = tid & 63;

    __shared__ __hip_bfloat16 shA[TM * LDA];
    __shared__ __hip_bfloat16 shB[TN * LDA];

    int m0 = mblk * TM;
    int n0 = nblk * TN;

    int rowl0 = tid >> 2;             // 0..63
    int rowl1 = rowl0 + 64;           // 64..127
    int k8    = (tid & 3) * 8;
    int ar0 = m0 + rowl0, ar1 = m0 + rowl1;
    int sa0 = (ar0 & ~511) | (dir ? (511 - (ar0 & 511)) : (ar0 & 511));
    int sa1 = (ar1 & ~511) | (dir ? (511 - (ar1 & 511)) : (ar1 & 511));
    const __hip_bfloat16* kbase = kT + (size_t)dir * G_ * E_;

    f32x16 acc[4] = {};

    int lm = lane & 31;
    int kq = (lane >> 5) * 8;

    for (int k0 = 0; k0 < E_; k0 += BK) {
        __syncthreads();
        *(short8*)&shA[rowl0 * LDA + k8] = *(const short8*)(xbf + (size_t)sa0 * E_ + k0 + k8);
        *(short8*)&shA[rowl1 * LDA + k8] = *(const short8*)(xbf + (size_t)sa1 * E_ + k0 + k8);
        *(short8*)&shB[rowl0 * LDA + k8] = *(const short8*)(kbase + (size_t)(n0 + rowl0) * E_ + k0 + k8);
        *(short8*)&shB[rowl1 * LDA + k8] = *(const short8*)(kbase + (size_t)(n0 + rowl1) * E_ + k0 + k8);
        __syncthreads();

#pragma unroll
        for (int kk = 0; kk < BK; kk += 16) {
            short8 afrag = *(const short8*)&shA[(wave * 32 + lm) * LDA + kk + kq];
#pragma unroll
            for (int j = 0; j < 4; ++j) {
                short8 bfrag = *(const short8*)&shB[(j * 32 + lm) * LDA + kk + kq];
                acc[j] = __builtin_amdgcn_mfma_f32_32x32x16_bf16(afrag, bfrag, acc[j], 0, 0, 0);
            }
        }
    }

    const float* bias = dir ? bias_b : bias_f;
#pragma unroll
    for (int j = 0; j < 4; ++j) {
        int col = n0 + j * 32 + lm;
        float bv = bias[col];
#pragma unroll
        for (int reg = 0; reg < 16; ++reg) {
            int row = m0 + wave * 32 + (reg & 3) + 8 * (reg >> 2) + 4 * (lane >> 5);
            xz[((size_t)dir * MROWS + row) * G_ + col] = __float2bfloat16(acc[j][reg] + bv);
        }
    }
}

// ---------------- recurrent scan: 2-CU split, rec fully VGPR-resident ----------------
__device__ inline float sigmoidf(float x) { return 1.f / (1.f + __expf(-x)); }
__device__ inline float bfu(unsigned int u) { return __builtin_bit_cast(float, u << 16); }

// r11. 16 wgs: pair = wg&7 encodes (bg = pair&3, dir = pair>>2); half = wg>>3.
// Each wg owns h-cols [half*128, half*128+128) (= 512 gate-cols): rec slice 256 KB
// lives ENTIRELY in 128 asm-pinned VGPRs/thread (32 uint4) — zero per-step rec traffic
// (the resource every previous design was bound on). Transposed MFMA (r10 layouts):
//   Z^T = rec^T(A) x H^T(B), mfma_f32_16x16x32_f16.
//   A-frag: lane m=l&15 (gc-in-tile), k=(l>>4)*8+j.  B-frag: lane n=l&15 (batch), same k.
//   C-frag: col=l&15=batch, row=(l>>4)*4+reg=gc-in-tile [guide m89-verified].
// Wave w owns hcols half*128+w*16..+16: tiles Tg(r)=r*16+half*8+w for gate regions
// r=i,f,c,o; the SAME reg index across the 4 region-accs gives all four gates of one
// (batch,hcol) IN-LANE -> gates need no exchange. c-state in VGPRs.
// Per step the partner halves exchange h (4 KB each way) via global hx + counter
// handshake (device-scope fences; correct under any XCD placement — G16):
//   write own h' -> LDS直 (own half) and -> hx[slot=s&1]; __syncthreads (drains vmcnt);
//   tid0: __threadfence (release: L2 writeback) -> ctr[me]++ -> spin ctr[partner] > s
//         -> __threadfence (acquire: invalidate stale L1/L2); __syncthreads;
//   threads<256 copy partner's 4 KB hx -> LDS; __syncthreads.
// Slot safety: writer rewrites slot s&1 at step s+2 only after observing partner
// published s+1, which (program order) implies partner finished READING slot s&1.
// ctr is memset 0 per launch. Pair {g,g+8} lands same-XCD under blockIdx%8 (fast path);
// the protocol does not DEPEND on it.
__global__ __launch_bounds__(512, 2) void scan_kernel(
        const __hip_bfloat16* __restrict__ xz,    // [2][MROWS][G]
        const uint4* __restrict__ recF,           // [2][64][8][64] uint4 (A-frags)
        const float* __restrict__ Wd,             // [S*H][2]
        const float* __restrict__ bd,             // [2]
        int* __restrict__ ctr,                    // [8][2], zeroed per launch
        uint4* __restrict__ hx,                   // [8][2 slots][512]
        float* __restrict__ out) {                // [B][2], pre-zeroed
    int wg = blockIdx.x;
    int pair = wg & 7, half = wg >> 3;
    int bg = pair & 3, dir = pair >> 2;
    int tid = threadIdx.x;
    int w = tid >> 6, l = tid & 63, l15 = l & 15, l4 = l >> 4;

    // H in B-frag order: uint4 idx = ks*64 + kq*16 + batch  (k = ks*32+kq*8+j). 8KB x2.
    __shared__ uint4 HlU[2][512];
    __shared__ float rbuf[8][16][2];

    int hbase = half * 128 + w * 16;     // wave's first hcol
    int gb = hbase + l4 * 4;             // lane's first hcol (C-frag rows gb..gb+3)

    // ---- asm-pinned preload of this wg's rec slice: 32 uint4 = 128 VGPRs ----
    // tile Tg(r) = r*16 + half*8 + w; uint4 index (Tg*8+ks)*64 + l.
    u32x4 rr[4][8];
    {
        const uint4* rbase = recF + (size_t)dir * 32768 + (size_t)(half * 8 + w) * 8 * 64 + l;
        unsigned long long a0 = (unsigned long long)(const void*)rbase;
#pragma unroll
        for (int r = 0; r < 4; ++r)
#pragma unroll
            for (int ks = 0; ks < 8; ++ks) {
                unsigned long long ka = a0 + (unsigned long long)(r * 131072 + ks * 1024);
                asm volatile("global_load_dwordx4 %0, %1, off" : "=v"(rr[r][ks]) : "v"(ka));
            }
        asm volatile("s_waitcnt vmcnt(0)" ::: "memory");
    }

    // h(-1) = 0
    HlU[0][tid] = make_uint4(0u, 0u, 0u, 0u);

    const __hip_bfloat16* xzb = xz + ((size_t)dir * MROWS + (size_t)(bg * 16 + l15) * S_) * G_;

    // prefetch xz for s=0: 4 bf16 per region at gc = r*256 + gb
    uint2 nx[4];
#pragma unroll
    for (int r = 0; r < 4; ++r)
        nx[r] = *(const uint2*)(xzb + (r * 256 + gb));

    int* cme = ctr + pair * 2 + half;
    int* cot = ctr + pair * 2 + (half ^ 1);
    uint4* hxp = hx + (size_t)pair * 1024;

    // this lane's h'-publish position (B-frag order), lane-constant:
    int eks = half * 4 + (w >> 1);
    int ekq = (w & 1) * 2 + (l4 >> 1);
    int eidx16 = ((eks * 4 + ekq) * 16 + l15) * 8 + (l4 & 1) * 4;   // f16 units

    f32x4 c_ = {0.f, 0.f, 0.f, 0.f};
    float pl0 = 0.f, pl1 = 0.f;
    __syncthreads();

    int p = 0;
    for (int s = 0; s < S_; ++s) {
        int tt = dir ? (S_ - 1 - s) : s;

        // acc init = xz (bias folded in by the GEMM); element e <-> row gb+e
        f32x4 acc[4];
#pragma unroll
        for (int r = 0; r < 4; ++r) {
            uint2 v = nx[r];
            f32x4 a;
            a[0] = bfu(v.x & 0xffffu); a[1] = bfu(v.x >> 16);
            a[2] = bfu(v.y & 0xffffu); a[3] = bfu(v.y >> 16);
            acc[r] = a;
        }
        // prefetch next step's xz now (latency hides under K-loop; regs survive fences)
        int sn = (s + 1 < S_) ? (s + 1) : (S_ - 1);
#pragma unroll
        for (int r = 0; r < 4; ++r)
            nx[r] = *(const uint2*)(xzb + (size_t)sn * G_ + (r * 256 + gb));

        // Wd rows tt*256 + gb .. +3 (issued early, consumed after gates)
        const float* wdp = Wd + (size_t)(tt * 256 + gb) * 2;
        float4 w0 = *(const float4*)(wdp);
        float4 w1 = *(const float4*)(wdp + 4);

        // K loop: 8 ksteps x 4 region-tiles; A from VGPR, B from LDS
        const uint4* hb = &HlU[p][0];
#pragma unroll
        for (int ks = 0; ks < 8; ++ks) {
            h8 hf = __builtin_bit_cast(h8, hb[ks * 64 + l4 * 16 + l15]);
#pragma unroll
            for (int r = 0; r < 4; ++r)
                acc[r] = __builtin_amdgcn_mfma_f32_16x16x32_f16(
                    __builtin_bit_cast(h8, rr[r][ks]), hf, acc[r], 0, 0, 0);
        }

        // gates: regions r = i,f,c,o fully in-lane
        f32x4 hh;
#pragma unroll
        for (int e = 0; e < 4; ++e) {
            float ig = sigmoidf(acc[0][e]);
            float fg = sigmoidf(acc[1][e]);
            float og = sigmoidf(acc[3][e]);
            float cand = fmaxf(acc[2][e], 0.f);
            float cn = fg * c_[e] + ig * cand;
            c_[e] = cn;
            hh[e] = og * fmaxf(cn, 0.f);
        }
        pl0 += hh[0] * w0.x + hh[1] * w0.z + hh[2] * w1.x + hh[3] * w1.z;
        pl1 += hh[0] * w0.y + hh[1] * w0.w + hh[2] * w1.y + hh[3] * w1.w;

        if (s < S_ - 1) {
            unsigned int lo = (unsigned int)__builtin_bit_cast(unsigned short, (_Float16)hh[0]) |
                              ((unsigned int)__builtin_bit_cast(unsigned short, (_Float16)hh[1]) << 16);
            unsigned int hi2 = (unsigned int)__builtin_bit_cast(unsigned short, (_Float16)hh[2]) |
                               ((unsigned int)__builtin_bit_cast(unsigned short, (_Float16)hh[3]) << 16);
            uint2 st; st.x = lo; st.y = hi2;
            // own half straight into next LDS buffer (no global round trip)
            *(uint2*)((char*)&HlU[p ^ 1][0] + eidx16 * 2) = st;
            // and to global for the partner
            *(uint2*)((char*)(hxp + (size_t)(s & 1) * 512) + eidx16 * 2) = st;

            __syncthreads();   // all threads' stores vmcnt/lgkm-drained; wg synced
            if (tid == 0) {
                __threadfence();                                   // release: push L2 -> coherence point
                __hip_atomic_fetch_add(cme, 1, __ATOMIC_RELAXED, __HIP_MEMORY_SCOPE_AGENT);
                while (__hip_atomic_load(cot, __ATOMIC_RELAXED, __HIP_MEMORY_SCOPE_AGENT) <= s)
                    __builtin_amdgcn_s_sleep(1);
                __threadfence();                                   // acquire: invalidate stale L1/L2
            }
            __syncthreads();
            // copy partner's 4 KB (256 uint4, contiguous ks range) into next LDS buffer
            int ph = half ^ 1;
            if (tid < 256)
                HlU[p ^ 1][ph * 256 + tid] = hxp[(size_t)(s & 1) * 512 + ph * 256 + tid];
            __syncthreads();
            p ^= 1;
        }
    }

    // reduce pl over l4 groups (same batch l15), then across waves
#pragma unroll
    for (int off = 16; off <= 32; off <<= 1) {
        pl0 += __shfl_xor(pl0, off);
        pl1 += __shfl_xor(pl1, off);
    }
    if (l < 16) { rbuf[w][l][0] = pl0; rbuf[w][l][1] = pl1; }
    __syncthreads();
    if (tid < 16) {
        float t0 = 0.f, t1 = 0.f;
#pragma unroll
        for (int ww = 0; ww < 8; ++ww) { t0 += rbuf[ww][tid][0]; t1 += rbuf[ww][tid][1]; }
        if (dir == 0 && half == 0) { t0 += bd[0]; t1 += bd[1]; }
        atomicAdd(&out[(bg * 16 + tid) * 2 + 0], t0);
        atomicAdd(&out[(bg * 16 + tid) * 2 + 1], t1);
    }
}

// ---------------- launch ----------------
extern "C" void kernel_launch(void* const* d_in, const int* in_sizes, int n_in,
                              void* d_out, int out_size, void* d_ws, size_t ws_size,
                              hipStream_t stream) {
    const float* x        = (const float*)d_in[0];
    const float* kernel_f = (const float*)d_in[1];
    const float* rec_f    = (const float*)d_in[2];
    const float* bias_f   = (const float*)d_in[3];
    const float* kernel_b = (const float*)d_in[4];
    const float* rec_b    = (const float*)d_in[5];
    const float* bias_b   = (const float*)d_in[6];
    const float* Wd       = (const float*)d_in[7];
    const float* bd       = (const float*)d_in[8];
    float* out = (float*)d_out;

    // workspace layout
    char* w = (char*)d_ws;
    __hip_bfloat16* xz  = (__hip_bfloat16*)w;                       // 2*32768*1024*2 = 134217728
    __hip_bfloat16* xbf = (__hip_bfloat16*)(w + 134217728);         // 64*512*768*2   = 50331648
    __hip_bfloat16* kT  = (__hip_bfloat16*)(w + 184549376);         // 2*1024*768*2   = 3145728
    uint4*         recF = (uint4*)        (w + 187695104);          // 2*64*8*64*16   = 1048576
    // scan-phase scratch carved out of xbf (dead after gemm; stream order guarantees safety)
    uint4* hx  = (uint4*)(w + 134217728);                           // 8*2*512*16 = 131072
    int*   ctr = (int*)  (w + 134217728 + 131072);                  // 64 B

    // prep
    int nx = B_ * S_ * E_;
    cast_x_kernel<<<nx / (256 * 4), 256, 0, stream>>>(x, xbf, nx);
    prep_kT_kernel<<<dim3((E_ * G_) / 256, 2), 256, 0, stream>>>(kernel_f, kernel_b, kT);
    prep_recF_kernel<<<256, 256, 0, stream>>>(rec_f, rec_b, recF);

    // xz GEMM: grid (N/128, M/128, dirs)
    gemm_xz_kernel<<<dim3(G_ / TN, MROWS / TM, 2), 256, 0, stream>>>(xbf, kT, bias_f, bias_b, xz);

    // zero logits + handshake counters, then scan
    hipMemsetAsync(d_out, 0, (size_t)out_size * sizeof(float), stream);
    hipMemsetAsync(ctr, 0, 64, stream);
    scan_kernel<<<dim3(16), 512, 0, stream>>>(xz, recF, Wd, bd, ctr, hx, out);
}

// Round 7
// 1128.573 us; speedup vs baseline: 1.6128x; 1.6128x over previous
//
#include <hip/hip_runtime.h>
#include <hip/hip_bf16.h>
#include <hip/hip_fp16.h>

// Problem: B=64, S=512, E=768, H=256 (4H=1024). Bidirectional relu-LSTM + dense(2).
#define B_ 64
#define S_ 512
#define E_ 768
#define H_ 256
#define G_ 1024  // 4H
#define MROWS 32768  // B*S per direction

typedef float f32x4 __attribute__((ext_vector_type(4)));
typedef float f32x16 __attribute__((ext_vector_type(16)));
typedef short short8 __attribute__((ext_vector_type(8)));
typedef _Float16 v2h __attribute__((ext_vector_type(2)));
typedef unsigned int u32x4 __attribute__((ext_vector_type(4)));

// ---------------- prep kernels ----------------

__global__ void cast_x_kernel(const float* __restrict__ x, __hip_bfloat16* __restrict__ xbf, int n) {
    int i = (blockIdx.x * 256 + threadIdx.x) * 4;
    if (i >= n) return;
    float4 v = *(const float4*)(x + i);
    xbf[i + 0] = __float2bfloat16(v.x);
    xbf[i + 1] = __float2bfloat16(v.y);
    xbf[i + 2] = __float2bfloat16(v.z);
    xbf[i + 3] = __float2bfloat16(v.w);
}

// kernel [E][G] fp32 -> kT [dir][G][E] bf16 (transposed for MFMA B-fragments)
__global__ void prep_kT_kernel(const float* __restrict__ kf, const float* __restrict__ kb,
                               __hip_bfloat16* __restrict__ kT) {
    int idx = blockIdx.x * 256 + threadIdx.x;   // over E_*G_
    int dir = blockIdx.y;
    const float* src = dir ? kb : kf;
    int k = idx >> 10;        // E index
    int n = idx & 1023;       // G index
    float v = src[idx];       // coalesced read (n fast)
    kT[(size_t)dir * G_ * E_ + (size_t)n * E_ + k] = __float2bfloat16(v);
}

// rec [256][1024] fp32 -> recQ [dir][32][1024] uint4: half2 pairs of k = 8kk..8kk+7, col g
__global__ void prep_recQ_kernel(const float* __restrict__ rf, const float* __restrict__ rb,
                                 unsigned int* __restrict__ recQ) {
    int idx = blockIdx.x * 256 + threadIdx.x;   // over 32*1024*4 = 131072
    int dir = blockIdx.y;
    const float* src = dir ? rb : rf;
    int g  = idx & 1023;
    int u  = (idx >> 10) & 3;
    int kk = idx >> 12;
    int k0 = 8 * kk + 2 * u;
    float a = src[(size_t)k0 * G_ + g];
    float b = src[(size_t)(k0 + 1) * G_ + g];
    v2h p;
    p[0] = (_Float16)a;
    p[1] = (_Float16)b;
    recQ[(size_t)dir * 131072 + (size_t)kk * 4096 + g * 4 + u] = __builtin_bit_cast(unsigned int, p);
}

// ---------------- xz GEMM: m97-structure (global_load_lds w16 + XCD swizzle) --------
#define TM 128
#define TN 128
#define BK 32

__device__ inline void glds16(const __hip_bfloat16* g, void* lds) {
    __builtin_amdgcn_global_load_lds(
        (const __attribute__((address_space(1))) unsigned int*)g,
        (__attribute__((address_space(3))) unsigned int*)lds, 16, 0, 0);
}

// r12 GEMM upgrade (scan untouched): the ladder's m93->m97 step.
//  - Staging via global_load_lds width=16: per (wave,j) inst, lane l supplies the
//    per-lane GLOBAL address (row = wave*32+j*16+(l>>2), col = (l&3)*8) and the HW
//    writes LDS at wave-uniform base + l*16 -> exactly linear [128][32] row-major.
//    (Per-lane global src is allowed; LDS dest must be linear — guide §5 caveat.)
//  - Linear [128][32] LDS (no pad): known ~2-bank conflict pattern on the b128
//    fragment reads, absorbed at m97's 874 TF (m98 PMC) — accepted.
//  - XCD-aware bijective swizzle: physical block p -> virtual v=(p&7)*512+(p>>3);
//    the 8 nblks sharing one A-panel are v-consecutive -> same XCD -> A-panel
//    fetched once per XCD instead of 8x across XCDs. nwg=4096, %8==0.
//  - MFMA loop / accumulation order / epilogue identical to the passing kernel.
__global__ __launch_bounds__(256) void gemm_xz_kernel(
        const __hip_bfloat16* __restrict__ xbf,   // [B*S][E]
        const __hip_bfloat16* __restrict__ kT,    // [2][G][E]
        const float* __restrict__ bias_f, const float* __restrict__ bias_b,
        __hip_bfloat16* __restrict__ xz) {        // [2][MROWS][G]
    int p = blockIdx.x;                 // 0..4095 physical
    int v = (p & 7) * 512 + (p >> 3);   // bijective XCD chunking
    int nblk = v & 7;
    int g    = v >> 3;                  // 0..511
    int mblk = g & 255;
    int dir  = g >> 8;
    int tid  = threadIdx.x;
    int wave = tid >> 6, lane = tid & 63;

    __shared__ __hip_bfloat16 shA[TM * BK];
    __shared__ __hip_bfloat16 shB[TN * BK];

    int m0 = mblk * TM;
    int n0 = nblk * TN;

    // staging geometry: inst (wave, j) covers tile rows wave*32+j*16 .. +16
    int r0 = wave * 32 + (lane >> 2);
    int r1 = r0 + 16;
    int c8 = (lane & 3) * 8;
    int ar0 = m0 + r0, ar1 = m0 + r1;
    int sa0 = (ar0 & ~511) | (dir ? (511 - (ar0 & 511)) : (ar0 & 511));
    int sa1 = (ar1 & ~511) | (dir ? (511 - (ar1 & 511)) : (ar1 & 511));
    const __hip_bfloat16* kbase = kT + (size_t)dir * G_ * E_;
    const __hip_bfloat16* gA0 = xbf + (size_t)sa0 * E_ + c8;
    const __hip_bfloat16* gA1 = xbf + (size_t)sa1 * E_ + c8;
    const __hip_bfloat16* gB0 = kbase + (size_t)(n0 + r0) * E_ + c8;
    const __hip_bfloat16* gB1 = kbase + (size_t)(n0 + r1) * E_ + c8;
    char* lA0 = (char*)shA + wave * 2048;
    char* lA1 = (char*)shA + wave * 2048 + 1024;
    char* lB0 = (char*)shB + wave * 2048;
    char* lB1 = (char*)shB + wave * 2048 + 1024;

    f32x16 acc[4] = {};

    int lm = lane & 31;
    int kq = (lane >> 5) * 8;

    for (int k0 = 0; k0 < E_; k0 += BK) {
        __syncthreads();                         // previous iter's ds_reads done
        glds16(gA0 + k0, lA0);
        glds16(gA1 + k0, lA1);
        glds16(gB0 + k0, lB0);
        glds16(gB1 + k0, lB1);
        __syncthreads();                         // drains vmcnt: staged data visible

#pragma unroll
        for (int kk = 0; kk < BK; kk += 16) {
            short8 afrag = *(const short8*)&shA[(wave * 32 + lm) * BK + kk + kq];
#pragma unroll
            for (int j = 0; j < 4; ++j) {
                short8 bfrag = *(const short8*)&shB[(j * 32 + lm) * BK + kk + kq];
                acc[j] = __builtin_amdgcn_mfma_f32_32x32x16_bf16(afrag, bfrag, acc[j], 0, 0, 0);
            }
        }
    }

    const float* bias = dir ? bias_b : bias_f;
#pragma unroll
    for (int j = 0; j < 4; ++j) {
        int col = n0 + j * 32 + lm;
        float bv = bias[col];
#pragma unroll
        for (int reg = 0; reg < 16; ++reg) {
            int row = m0 + wave * 32 + (reg & 3) + 8 * (reg >> 2) + 4 * (lane >> 5);
            xz[((size_t)dir * MROWS + row) * G_ + col] = __float2bfloat16(acc[j][reg] + bv);
        }
    }
}

// ---------------- recurrent scan (byte-identical to the verified r8, 885 us) ----------
__device__ inline float dot2f16(unsigned int rbits, unsigned int hbits, float acc) {
#if __has_builtin(__builtin_amdgcn_fdot2)
    return __builtin_amdgcn_fdot2(__builtin_bit_cast(v2h, rbits),
                                  __builtin_bit_cast(v2h, hbits), acc, false);
#else
    v2h r = __builtin_bit_cast(v2h, rbits);
    v2h h = __builtin_bit_cast(v2h, hbits);
    return acc + (float)r[0] * (float)h[0] + (float)r[1] * (float)h[1];
#endif
}

__device__ inline float sigmoidf(float x) { return 1.f / (1.f + __expf(-x)); }

#define KKREG 24   // kk-groups (8 k each) in VGPRs: 24*2 cols = 48 uint4 = 192 VGPRs
#define KKLDS 8    // kk-groups in LDS: 8 * 16 KB = 128 KB
__global__ __launch_bounds__(512) void scan_kernel(
        const __hip_bfloat16* __restrict__ xz,    // [2][MROWS][G]
        const uint4* __restrict__ recQ,           // [2][32][1024] uint4
        const float* __restrict__ Wd,             // [S*H][2]
        const float* __restrict__ bd,             // [2]
        float* __restrict__ out) {                // [B][2], pre-zeroed
    int b = blockIdx.x, dir = blockIdx.y, tid = threadIdx.x;
    __shared__ __align__(16) uint4 sh_rec[KKLDS * G_];   // 131072 B
    __shared__ __align__(16) _Float16 sh_h[2][H_];       // 1 KB, double-buffered h
    __shared__ float rbuf[16];

    int w = tid >> 6, lane = tid & 63, lm = lane & 31, hi = lane >> 5;
    int col = w * 32 + lm;       // h column 0..255
    int g0  = col + hi * 512;    // gate col: i (hi=0) or c (hi=1)
    int g1  = g0 + 256;          // gate col: f (hi=0) or o (hi=1)

    const uint4* rqbase = recQ + (size_t)dir * 32768;

    // ---- asm-origin preload of rec kk=0..23 for cols g0,g1 (cannot be sunk) ----
    u32x4 rr0[KKREG], rr1[KKREG];
    {
        unsigned long long a0 = (unsigned long long)(const void*)(rqbase + g0);
        unsigned long long a1 = (unsigned long long)(const void*)(rqbase + g1);
#pragma unroll
        for (int kk = 0; kk < KKREG; ++kk) {
            unsigned long long ka0 = a0 + (unsigned long long)kk * 16384ull;
            unsigned long long ka1 = a1 + (unsigned long long)kk * 16384ull;
            asm volatile("global_load_dwordx4 %0, %1, off" : "=v"(rr0[kk]) : "v"(ka0));
            asm volatile("global_load_dwordx4 %0, %1, off" : "=v"(rr1[kk]) : "v"(ka1));
        }
        asm volatile("s_waitcnt vmcnt(0)" ::: "memory");
    }

    // ---- stage rec kk=24..31 (all 1024 cols) into LDS, coalesced ----
#pragma unroll
    for (int j = 0; j < KKLDS * 2; ++j)
        sh_rec[j * 512 + tid] = rqbase[KKREG * 1024 + j * 512 + tid];

    if (tid < H_) sh_h[0][tid] = (_Float16)0.f;
    float c = 0.f, pl0 = 0.f, pl1 = 0.f;
    float wsel = hi ? 0.f : 1.f;
    const __hip_bfloat16* xrb = xz + ((size_t)dir * MROWS + (size_t)b * S_) * G_;
    __syncthreads();

    // prefetch step 0's xz/Wd (plain loads, compiler-tracked)
    float nxz0 = __bfloat162float(xrb[g0]);
    float nxz1 = __bfloat162float(xrb[g1]);
    int t0i = dir ? (S_ - 1) : 0;
    float2 nwv = ((const float2*)Wd)[t0i * H_ + col];

    int p = 0;
    for (int s = 0; s < S_; ++s) {
        // consume prefetched values for this step
        float xz0 = nxz0, xz1 = nxz1;
        float2 wv = nwv;

        // issue prefetch for s+1 NOW: the whole dot phase covers its latency
        int sn = (s + 1 < S_) ? (s + 1) : (S_ - 1);
        int tn = dir ? (S_ - 1 - sn) : sn;
        nxz0 = __bfloat162float(xrb[(size_t)sn * G_ + g0]);
        nxz1 = __bfloat162float(xrb[(size_t)sn * G_ + g1]);
        nwv  = ((const float2*)Wd)[tn * H_ + col];

        const uint4* hp = (const uint4*)&sh_h[p][0];          // 32 uint4 = 256 halves
        float z0a = 0.f, z0b = 0.f, z1a = 0.f, z1b = 0.f;

        // register part (kk 0..23): rec from VGPR, h broadcast from LDS
#pragma unroll
        for (int kk = 0; kk < KKREG; ++kk) {
            uint4 hv = hp[kk];                                 // wave-uniform broadcast
            u32x4 r0 = rr0[kk];
            u32x4 r1 = rr1[kk];
            z0a = dot2f16(r0.x, hv.x, z0a); z0b = dot2f16(r0.y, hv.y, z0b);
            z0a = dot2f16(r0.z, hv.z, z0a); z0b = dot2f16(r0.w, hv.w, z0b);
            z1a = dot2f16(r1.x, hv.x, z1a); z1b = dot2f16(r1.y, hv.y, z1b);
            z1a = dot2f16(r1.z, hv.z, z1a); z1b = dot2f16(r1.w, hv.w, z1b);
        }
        // LDS part (kk 24..31): lanes read consecutive 16B chunks
#pragma unroll
        for (int j = 0; j < KKLDS; ++j) {
            uint4 hv = hp[KKREG + j];
            uint4 r0 = sh_rec[j * 1024 + g0];
            uint4 r1 = sh_rec[j * 1024 + g1];
            z0a = dot2f16(r0.x, hv.x, z0a); z0b = dot2f16(r0.y, hv.y, z0b);
            z0a = dot2f16(r0.z, hv.z, z0a); z0b = dot2f16(r0.w, hv.w, z0b);
            z1a = dot2f16(r1.x, hv.x, z1a); z1b = dot2f16(r1.y, hv.y, z1b);
            z1a = dot2f16(r1.z, hv.z, z1a); z1b = dot2f16(r1.w, hv.w, z1b);
        }

        float z0 = z0a + z0b + xz0;    // gate i (hi=0) or c (hi=1)
        float z1 = z1a + z1b + xz1;    // gate f (hi=0) or o (hi=1)

        // register-only exchange with the partner half-wave (lane ^ 32)
        float zx0 = __shfl_xor(z0, 32);
        float zx1 = __shfl_xor(z1, 32);
        float zi = hi ? zx0 : z0;
        float zf = hi ? zx1 : z1;
        float zc = hi ? z0 : zx0;
        float zo = hi ? z1 : zx1;

        // gates — both halves compute identical c/h (redundant, cheap, divergence-free)
        float ig = sigmoidf(zi);
        float fg = sigmoidf(zf);
        float og = sigmoidf(zo);
        float cc = fmaxf(zc, 0.f);
        c = fg * c + ig * cc;
        float h = og * fmaxf(c, 0.f);
        if (hi == 0) sh_h[p ^ 1][col] = (_Float16)h;           // write NEXT buffer

        pl0 = fmaf(h, wv.x * wsel, pl0);   // wsel=0 on hi=1 lanes (no double count)
        pl1 = fmaf(h, wv.y * wsel, pl1);

        __syncthreads();                                       // new h visible
        p ^= 1;
    }

    // reduction: contributions live in lanes 0..31 of every wave (hi lanes are 0)
#pragma unroll
    for (int off = 32; off > 0; off >>= 1) {
        pl0 += __shfl_down(pl0, off);
        pl1 += __shfl_down(pl1, off);
    }
    if (lane == 0) {
        rbuf[w] = pl0; rbuf[8 + w] = pl1;
    }
    __syncthreads();
    if (tid == 0) {
        float t0 = 0.f, t1 = 0.f;
#pragma unroll
        for (int i = 0; i < 8; ++i) { t0 += rbuf[i]; t1 += rbuf[8 + i]; }
        atomicAdd(&out[b * 2 + 0], t0);
        atomicAdd(&out[b * 2 + 1], t1);
    }
    if (dir == 0 && tid < 2) atomicAdd(&out[b * 2 + tid], bd[tid]);
}

// ---------------- launch ----------------
extern "C" void kernel_launch(void* const* d_in, const int* in_sizes, int n_in,
                              void* d_out, int out_size, void* d_ws, size_t ws_size,
                              hipStream_t stream) {
    const float* x        = (const float*)d_in[0];
    const float* kernel_f = (const float*)d_in[1];
    const float* rec_f    = (const float*)d_in[2];
    const float* bias_f   = (const float*)d_in[3];
    const float* kernel_b = (const float*)d_in[4];
    const float* rec_b    = (const float*)d_in[5];
    const float* bias_b   = (const float*)d_in[6];
    const float* Wd       = (const float*)d_in[7];
    const float* bd       = (const float*)d_in[8];
    float* out = (float*)d_out;

    // workspace layout
    char* w = (char*)d_ws;
    __hip_bfloat16* xz  = (__hip_bfloat16*)w;                       // 2*32768*1024*2 = 134217728
    __hip_bfloat16* xbf = (__hip_bfloat16*)(w + 134217728);         // 64*512*768*2   = 50331648
    __hip_bfloat16* kT  = (__hip_bfloat16*)(w + 184549376);         // 2*1024*768*2   = 3145728
    unsigned int*  recQ = (unsigned int*) (w + 187695104);          // 2*32*1024*16   = 1048576

    // prep
    int nx = B_ * S_ * E_;
    cast_x_kernel<<<nx / (256 * 4), 256, 0, stream>>>(x, xbf, nx);
    prep_kT_kernel<<<dim3((E_ * G_) / 256, 2), 256, 0, stream>>>(kernel_f, kernel_b, kT);
    prep_recQ_kernel<<<dim3(131072 / 256, 2), 256, 0, stream>>>(rec_f, rec_b, recQ);

    // xz GEMM: 1D grid with XCD-chunked decode (4096 wgs)
    gemm_xz_kernel<<<4096, 256, 0, stream>>>(xbf, kT, bias_f, bias_b, xz);

    // zero logits, then scan accumulates
    hipMemsetAsync(d_out, 0, (size_t)out_size * sizeof(float), stream);
    scan_kernel<<<dim3(B_, 2), 512, 0, stream>>>(xz, (const uint4*)recQ, Wd, bd, out);
}

// Round 8
// 1089.426 us; speedup vs baseline: 1.6707x; 1.0359x over previous
//
#include <hip/hip_runtime.h>
#include <hip/hip_bf16.h>
#include <hip/hip_fp16.h>

// Problem: B=64, S=512, E=768, H=256 (4H=1024). Bidirectional relu-LSTM + dense(2).
#define B_ 64
#define S_ 512
#define E_ 768
#define H_ 256
#define G_ 1024  // 4H
#define MROWS 32768  // B*S per direction

typedef float f32x4 __attribute__((ext_vector_type(4)));
typedef float f32x16 __attribute__((ext_vector_type(16)));
typedef short short8 __attribute__((ext_vector_type(8)));
typedef _Float16 v2h __attribute__((ext_vector_type(2)));
typedef unsigned int u32x4 __attribute__((ext_vector_type(4)));

// ---------------- prep kernels ----------------

__global__ void cast_x_kernel(const float* __restrict__ x, __hip_bfloat16* __restrict__ xbf, int n) {
    int i = (blockIdx.x * 256 + threadIdx.x) * 4;
    if (i >= n) return;
    float4 v = *(const float4*)(x + i);
    xbf[i + 0] = __float2bfloat16(v.x);
    xbf[i + 1] = __float2bfloat16(v.y);
    xbf[i + 2] = __float2bfloat16(v.z);
    xbf[i + 3] = __float2bfloat16(v.w);
}

// kernel [E][G] fp32 -> kT [dir][G][E] bf16 (transposed for MFMA B-fragments)
__global__ void prep_kT_kernel(const float* __restrict__ kf, const float* __restrict__ kb,
                               __hip_bfloat16* __restrict__ kT) {
    int idx = blockIdx.x * 256 + threadIdx.x;   // over E_*G_
    int dir = blockIdx.y;
    const float* src = dir ? kb : kf;
    int k = idx >> 10;        // E index
    int n = idx & 1023;       // G index
    float v = src[idx];       // coalesced read (n fast)
    kT[(size_t)dir * G_ * E_ + (size_t)n * E_ + k] = __float2bfloat16(v);
}

// rec [256][1024] fp32 -> recQ [dir][32][1024] uint4: half2 pairs of k = 8kk..8kk+7, col g
__global__ void prep_recQ_kernel(const float* __restrict__ rf, const float* __restrict__ rb,
                                 unsigned int* __restrict__ recQ) {
    int idx = blockIdx.x * 256 + threadIdx.x;   // over 32*1024*4 = 131072
    int dir = blockIdx.y;
    const float* src = dir ? rb : rf;
    int g  = idx & 1023;
    int u  = (idx >> 10) & 3;
    int kk = idx >> 12;
    int k0 = 8 * kk + 2 * u;
    float a = src[(size_t)k0 * G_ + g];
    float b = src[(size_t)(k0 + 1) * G_ + g];
    v2h p;
    p[0] = (_Float16)a;
    p[1] = (_Float16)b;
    recQ[(size_t)dir * 131072 + (size_t)kk * 4096 + g * 4 + u] = __builtin_bit_cast(unsigned int, p);
}

// ---------------- xz GEMM: BK=64, glds16 staging, full T2 XOR-swizzle ----------------
#define TM 128
#define TN 128
#define BK 64

__device__ inline void glds16(const __hip_bfloat16* g, void* lds) {
    __builtin_amdgcn_global_load_lds(
        (const __attribute__((address_space(1))) unsigned int*)g,
        (__attribute__((address_space(3))) unsigned int*)lds, 16, 0, 0);
}

// r13 GEMM: finish the m97-style upgrade properly.
//  - BK=64: 12 K-iters (vs 24), half the barrier events per FLOP. LDS 32 KB.
//  - T2 XOR-swizzle, BOTH sides (guide rule #21):
//      stage: glds16 writes LDS linearly (base + lane*16); lane l of inst i supplies
//             global (row = 8i + (l>>3), col8 = (l&7) ^ (row&7)) so that LDS chunk
//             (row, cs) holds tile chunk (row, cs ^ (row&7)).
//      read:  fragment chunk c of row r is at element r*64 + ((c ^ (r&7))*8).
//    Bank check: for fixed c, rows r..r+7 hit 8 distinct 16B slots covering all 32
//    banks -> fragment ds_read_b128 is volume-bound, no conflict (r12's linear
//    [128][32] had lanes at 64B stride -> ~16-way conflict that ate the glds gain).
//  - MFMA loop / accumulation order / epilogue / XCD block swizzle: unchanged.
__global__ __launch_bounds__(256) void gemm_xz_kernel(
        const __hip_bfloat16* __restrict__ xbf,   // [B*S][E]
        const __hip_bfloat16* __restrict__ kT,    // [2][G][E]
        const float* __restrict__ bias_f, const float* __restrict__ bias_b,
        __hip_bfloat16* __restrict__ xz) {        // [2][MROWS][G]
    int p = blockIdx.x;                 // 0..4095 physical
    int v = (p & 7) * 512 + (p >> 3);   // bijective XCD chunking
    int nblk = v & 7;
    int g    = v >> 3;                  // 0..511
    int mblk = g & 255;
    int dir  = g >> 8;
    int tid  = threadIdx.x;
    int wave = tid >> 6, lane = tid & 63;

    __shared__ __hip_bfloat16 shA[TM * BK];   // 16 KB, swizzled chunks
    __shared__ __hip_bfloat16 shB[TN * BK];   // 16 KB

    int m0 = mblk * TM;
    int n0 = nblk * TN;

    // staging geometry: 16 insts of 1KB per matrix per iter; wave w issues insts
    // 4w..4w+3 (rows 32w..32w+31). lane l -> row 8i+(l>>3), col chunk (l&7)^(row&7).
    const __hip_bfloat16* kbase = kT + (size_t)dir * G_ * E_;
    int rq[4], cq[4];        // per-q: row-in-tile, global col element
#pragma unroll
    for (int q = 0; q < 4; ++q) {
        int i = wave * 4 + q;
        int r = i * 8 + (lane >> 3);
        rq[q] = r;
        cq[q] = (((lane & 7) ^ (r & 7)) << 3);
    }
    // A rows go through the dir-flip; B rows are kT rows n0+r.
    const __hip_bfloat16* gA[4];
    const __hip_bfloat16* gB[4];
#pragma unroll
    for (int q = 0; q < 4; ++q) {
        int ar = m0 + rq[q];
        int sa = (ar & ~511) | (dir ? (511 - (ar & 511)) : (ar & 511));
        gA[q] = xbf + (size_t)sa * E_ + cq[q];
        gB[q] = kbase + (size_t)(n0 + rq[q]) * E_ + cq[q];
    }
    char* lA[4];
    char* lB[4];
#pragma unroll
    for (int q = 0; q < 4; ++q) {
        lA[q] = (char*)shA + (wave * 4 + q) * 1024;
        lB[q] = (char*)shB + (wave * 4 + q) * 1024;
    }

    f32x16 acc[4] = {};

    int lm = lane & 31;
    int kq = (lane >> 5) * 8;

    for (int k0 = 0; k0 < E_; k0 += BK) {
        __syncthreads();                         // previous iter's ds_reads done
#pragma unroll
        for (int q = 0; q < 4; ++q) {
            glds16(gA[q] + k0, lA[q]);
            glds16(gB[q] + k0, lB[q]);
        }
        __syncthreads();                         // drains vmcnt: staged data visible

#pragma unroll
        for (int kk = 0; kk < BK; kk += 16) {
            int ra = wave * 32 + lm;
            short8 afrag = *(const short8*)&shA[ra * 64 + ((((kk + kq) >> 3) ^ (ra & 7)) << 3)];
#pragma unroll
            for (int j = 0; j < 4; ++j) {
                int rb = j * 32 + lm;
                short8 bfrag = *(const short8*)&shB[rb * 64 + ((((kk + kq) >> 3) ^ (rb & 7)) << 3)];
                acc[j] = __builtin_amdgcn_mfma_f32_32x32x16_bf16(afrag, bfrag, acc[j], 0, 0, 0);
            }
        }
    }

    const float* bias = dir ? bias_b : bias_f;
#pragma unroll
    for (int j = 0; j < 4; ++j) {
        int col = n0 + j * 32 + lm;
        float bv = bias[col];
#pragma unroll
        for (int reg = 0; reg < 16; ++reg) {
            int row = m0 + wave * 32 + (reg & 3) + 8 * (reg >> 2) + 4 * (lane >> 5);
            xz[((size_t)dir * MROWS + row) * G_ + col] = __float2bfloat16(acc[j][reg] + bv);
        }
    }
}

// ---------------- recurrent scan (byte-identical to the verified r8, ~890 us) ----------
__device__ inline float dot2f16(unsigned int rbits, unsigned int hbits, float acc) {
#if __has_builtin(__builtin_amdgcn_fdot2)
    return __builtin_amdgcn_fdot2(__builtin_bit_cast(v2h, rbits),
                                  __builtin_bit_cast(v2h, hbits), acc, false);
#else
    v2h r = __builtin_bit_cast(v2h, rbits);
    v2h h = __builtin_bit_cast(v2h, hbits);
    return acc + (float)r[0] * (float)h[0] + (float)r[1] * (float)h[1];
#endif
}

__device__ inline float sigmoidf(float x) { return 1.f / (1.f + __expf(-x)); }

#define KKREG 24   // kk-groups (8 k each) in VGPRs: 24*2 cols = 48 uint4 = 192 VGPRs
#define KKLDS 8    // kk-groups in LDS: 8 * 16 KB = 128 KB
__global__ __launch_bounds__(512) void scan_kernel(
        const __hip_bfloat16* __restrict__ xz,    // [2][MROWS][G]
        const uint4* __restrict__ recQ,           // [2][32][1024] uint4
        const float* __restrict__ Wd,             // [S*H][2]
        const float* __restrict__ bd,             // [2]
        float* __restrict__ out) {                // [B][2], pre-zeroed
    int b = blockIdx.x, dir = blockIdx.y, tid = threadIdx.x;
    __shared__ __align__(16) uint4 sh_rec[KKLDS * G_];   // 131072 B
    __shared__ __align__(16) _Float16 sh_h[2][H_];       // 1 KB, double-buffered h
    __shared__ float rbuf[16];

    int w = tid >> 6, lane = tid & 63, lm = lane & 31, hi = lane >> 5;
    int col = w * 32 + lm;       // h column 0..255
    int g0  = col + hi * 512;    // gate col: i (hi=0) or c (hi=1)
    int g1  = g0 + 256;          // gate col: f (hi=0) or o (hi=1)

    const uint4* rqbase = recQ + (size_t)dir * 32768;

    // ---- asm-origin preload of rec kk=0..23 for cols g0,g1 (cannot be sunk) ----
    u32x4 rr0[KKREG], rr1[KKREG];
    {
        unsigned long long a0 = (unsigned long long)(const void*)(rqbase + g0);
        unsigned long long a1 = (unsigned long long)(const void*)(rqbase + g1);
#pragma unroll
        for (int kk = 0; kk < KKREG; ++kk) {
            unsigned long long ka0 = a0 + (unsigned long long)kk * 16384ull;
            unsigned long long ka1 = a1 + (unsigned long long)kk * 16384ull;
            asm volatile("global_load_dwordx4 %0, %1, off" : "=v"(rr0[kk]) : "v"(ka0));
            asm volatile("global_load_dwordx4 %0, %1, off" : "=v"(rr1[kk]) : "v"(ka1));
        }
        asm volatile("s_waitcnt vmcnt(0)" ::: "memory");
    }

    // ---- stage rec kk=24..31 (all 1024 cols) into LDS, coalesced ----
#pragma unroll
    for (int j = 0; j < KKLDS * 2; ++j)
        sh_rec[j * 512 + tid] = rqbase[KKREG * 1024 + j * 512 + tid];

    if (tid < H_) sh_h[0][tid] = (_Float16)0.f;
    float c = 0.f, pl0 = 0.f, pl1 = 0.f;
    float wsel = hi ? 0.f : 1.f;
    const __hip_bfloat16* xrb = xz + ((size_t)dir * MROWS + (size_t)b * S_) * G_;
    __syncthreads();

    // prefetch step 0's xz/Wd (plain loads, compiler-tracked)
    float nxz0 = __bfloat162float(xrb[g0]);
    float nxz1 = __bfloat162float(xrb[g1]);
    int t0i = dir ? (S_ - 1) : 0;
    float2 nwv = ((const float2*)Wd)[t0i * H_ + col];

    int p = 0;
    for (int s = 0; s < S_; ++s) {
        // consume prefetched values for this step
        float xz0 = nxz0, xz1 = nxz1;
        float2 wv = nwv;

        // issue prefetch for s+1 NOW: the whole dot phase covers its latency
        int sn = (s + 1 < S_) ? (s + 1) : (S_ - 1);
        int tn = dir ? (S_ - 1 - sn) : sn;
        nxz0 = __bfloat162float(xrb[(size_t)sn * G_ + g0]);
        nxz1 = __bfloat162float(xrb[(size_t)sn * G_ + g1]);
        nwv  = ((const float2*)Wd)[tn * H_ + col];

        const uint4* hp = (const uint4*)&sh_h[p][0];          // 32 uint4 = 256 halves
        float z0a = 0.f, z0b = 0.f, z1a = 0.f, z1b = 0.f;

        // register part (kk 0..23): rec from VGPR, h broadcast from LDS
#pragma unroll
        for (int kk = 0; kk < KKREG; ++kk) {
            uint4 hv = hp[kk];                                 // wave-uniform broadcast
            u32x4 r0 = rr0[kk];
            u32x4 r1 = rr1[kk];
            z0a = dot2f16(r0.x, hv.x, z0a); z0b = dot2f16(r0.y, hv.y, z0b);
            z0a = dot2f16(r0.z, hv.z, z0a); z0b = dot2f16(r0.w, hv.w, z0b);
            z1a = dot2f16(r1.x, hv.x, z1a); z1b = dot2f16(r1.y, hv.y, z1b);
            z1a = dot2f16(r1.z, hv.z, z1a); z1b = dot2f16(r1.w, hv.w, z1b);
        }
        // LDS part (kk 24..31): lanes read consecutive 16B chunks
#pragma unroll
        for (int j = 0; j < KKLDS; ++j) {
            uint4 hv = hp[KKREG + j];
            uint4 r0 = sh_rec[j * 1024 + g0];
            uint4 r1 = sh_rec[j * 1024 + g1];
            z0a = dot2f16(r0.x, hv.x, z0a); z0b = dot2f16(r0.y, hv.y, z0b);
            z0a = dot2f16(r0.z, hv.z, z0a); z0b = dot2f16(r0.w, hv.w, z0b);
            z1a = dot2f16(r1.x, hv.x, z1a); z1b = dot2f16(r1.y, hv.y, z1b);
            z1a = dot2f16(r1.z, hv.z, z1a); z1b = dot2f16(r1.w, hv.w, z1b);
        }

        float z0 = z0a + z0b + xz0;    // gate i (hi=0) or c (hi=1)
        float z1 = z1a + z1b + xz1;    // gate f (hi=0) or o (hi=1)

        // register-only exchange with the partner half-wave (lane ^ 32)
        float zx0 = __shfl_xor(z0, 32);
        float zx1 = __shfl_xor(z1, 32);
        float zi = hi ? zx0 : z0;
        float zf = hi ? zx1 : z1;
        float zc = hi ? z0 : zx0;
        float zo = hi ? z1 : zx1;

        // gates — both halves compute identical c/h (redundant, cheap, divergence-free)
        float ig = sigmoidf(zi);
        float fg = sigmoidf(zf);
        float og = sigmoidf(zo);
        float cc = fmaxf(zc, 0.f);
        c = fg * c + ig * cc;
        float h = og * fmaxf(c, 0.f);
        if (hi == 0) sh_h[p ^ 1][col] = (_Float16)h;           // write NEXT buffer

        pl0 = fmaf(h, wv.x * wsel, pl0);   // wsel=0 on hi=1 lanes (no double count)
        pl1 = fmaf(h, wv.y * wsel, pl1);

        __syncthreads();                                       // new h visible
        p ^= 1;
    }

    // reduction: contributions live in lanes 0..31 of every wave (hi lanes are 0)
#pragma unroll
    for (int off = 32; off > 0; off >>= 1) {
        pl0 += __shfl_down(pl0, off);
        pl1 += __shfl_down(pl1, off);
    }
    if (lane == 0) {
        rbuf[w] = pl0; rbuf[8 + w] = pl1;
    }
    __syncthreads();
    if (tid == 0) {
        float t0 = 0.f, t1 = 0.f;
#pragma unroll
        for (int i = 0; i < 8; ++i) { t0 += rbuf[i]; t1 += rbuf[8 + i]; }
        atomicAdd(&out[b * 2 + 0], t0);
        atomicAdd(&out[b * 2 + 1], t1);
    }
    if (dir == 0 && tid < 2) atomicAdd(&out[b * 2 + tid], bd[tid]);
}

// ---------------- launch ----------------
extern "C" void kernel_launch(void* const* d_in, const int* in_sizes, int n_in,
                              void* d_out, int out_size, void* d_ws, size_t ws_size,
                              hipStream_t stream) {
    const float* x        = (const float*)d_in[0];
    const float* kernel_f = (const float*)d_in[1];
    const float* rec_f    = (const float*)d_in[2];
    const float* bias_f   = (const float*)d_in[3];
    const float* kernel_b = (const float*)d_in[4];
    const float* rec_b    = (const float*)d_in[5];
    const float* bias_b   = (const float*)d_in[6];
    const float* Wd       = (const float*)d_in[7];
    const float* bd       = (const float*)d_in[8];
    float* out = (float*)d_out;

    // workspace layout
    char* w = (char*)d_ws;
    __hip_bfloat16* xz  = (__hip_bfloat16*)w;                       // 2*32768*1024*2 = 134217728
    __hip_bfloat16* xbf = (__hip_bfloat16*)(w + 134217728);         // 64*512*768*2   = 50331648
    __hip_bfloat16* kT  = (__hip_bfloat16*)(w + 184549376);         // 2*1024*768*2   = 3145728
    unsigned int*  recQ = (unsigned int*) (w + 187695104);          // 2*32*1024*16   = 1048576

    // prep
    int nx = B_ * S_ * E_;
    cast_x_kernel<<<nx / (256 * 4), 256, 0, stream>>>(x, xbf, nx);
    prep_kT_kernel<<<dim3((E_ * G_) / 256, 2), 256, 0, stream>>>(kernel_f, kernel_b, kT);
    prep_recQ_kernel<<<dim3(131072 / 256, 2), 256, 0, stream>>>(rec_f, rec_b, recQ);

    // xz GEMM: 1D grid with XCD-chunked decode (4096 wgs)
    gemm_xz_kernel<<<4096, 256, 0, stream>>>(xbf, kT, bias_f, bias_b, xz);

    // zero logits, then scan accumulates
    hipMemsetAsync(d_out, 0, (size_t)out_size * sizeof(float), stream);
    scan_kernel<<<dim3(B_, 2), 512, 0, stream>>>(xz, (const uint4*)recQ, Wd, bd, out);
}